// Round 1
// baseline (245.675 us; speedup 1.0000x reference)
//
#include <hip/hip_runtime.h>
#include <hip/hip_bf16.h>

#define B_ 16
#define T_ 1024
#define D_ 512
#define H_ 8
#define DH_ 64
#define NEGF (-4294967296.0f)

typedef __attribute__((ext_vector_type(4))) float f32x4;
typedef __attribute__((ext_vector_type(8))) short bf16x8;
typedef __attribute__((ext_vector_type(4))) short bf16x4;

__device__ __forceinline__ short f2bf(float f) {
    union { float f; unsigned u; } v; v.f = f;
    unsigned r = v.u + 0x7FFF + ((v.u >> 16) & 1);
    return (short)(r >> 16);
}

// ---------------- weight transpose: W fp32 [K][N] -> Wt bf16 [N][K] ----------------
__global__ void wtrans_kernel(const float* __restrict__ W, short* __restrict__ Wt) {
    __shared__ float tile[64][65];
    const int t = threadIdx.x;
    const int kt = (blockIdx.x >> 3) * 64;
    const int nt = (blockIdx.x & 7) * 64;
#pragma unroll
    for (int i = 0; i < 4; ++i) {
        int idx = t + i * 256;            // 1024 float4s = 64x64 floats
        int r = idx >> 4, c4 = idx & 15;
        float4 v = *(const float4*)&W[(kt + r) * D_ + nt + c4 * 4];
        tile[r][c4 * 4 + 0] = v.x; tile[r][c4 * 4 + 1] = v.y;
        tile[r][c4 * 4 + 2] = v.z; tile[r][c4 * 4 + 3] = v.w;
    }
    __syncthreads();
#pragma unroll
    for (int i = 0; i < 2; ++i) {
        int idx = t + i * 256;            // 512 groups of 8
        int nr = idx >> 3, c8 = idx & 7;
        bf16x8 pk;
#pragma unroll
        for (int j = 0; j < 8; ++j) pk[j] = f2bf(tile[c8 * 8 + j][nr]);
        *(bf16x8*)&Wt[(nt + nr) * D_ + kt + c8 * 8] = pk;
    }
}

// ---------------- padding masks: sign(|row sum|) ----------------
__global__ void mask_kernel(const float* __restrict__ X, float* __restrict__ mask) {
    const int w = threadIdx.x >> 6, lane = threadIdx.x & 63;
    const int row = blockIdx.x * 4 + w;
    const float4* p = (const float4*)&X[(size_t)row * D_];
    float s = 0.f;
#pragma unroll
    for (int i = 0; i < 2; ++i) {
        float4 v = p[lane + 64 * i];
        s += v.x + v.y + v.z + v.w;
    }
#pragma unroll
    for (int m = 1; m < 64; m <<= 1) s += __shfl_xor(s, m);
    if (lane == 0) mask[row] = (s != 0.0f) ? 1.0f : 0.0f;
}

// ---------------- projection GEMM: dst[M,512] = bf16(X[M,512] @ W + bias) ----------------
// Wt is bf16 [N][K]. 128x128 tile, BK=64, 4 waves in 2x2, 16x16x32 MFMA.
__global__ __launch_bounds__(256) void proj_gemm(const float* __restrict__ X,
                                                 const short* __restrict__ Wt,
                                                 const float* __restrict__ bias,
                                                 short* __restrict__ dst) {
    __shared__ short As[128][72];
    __shared__ short Bs[128][72];
    const int t = threadIdx.x;
    const int m0 = blockIdx.x * 128, n0 = blockIdx.y * 128;
    const int lane = t & 63, w = t >> 6;
    const int wr = w >> 1, wc = w & 1;
    const int cl = lane & 15, g = lane >> 4;
    f32x4 acc[4][4] = {};
    for (int kt = 0; kt < D_; kt += 64) {
        // stage A: 128x64 fp32 -> bf16
#pragma unroll
        for (int i = 0; i < 8; ++i) {
            int idx = t + 256 * i;        // 2048 float4s
            int r = idx >> 4, c4 = idx & 15;
            float4 v = *(const float4*)&X[(size_t)(m0 + r) * D_ + kt + c4 * 4];
            bf16x4 pk;
            pk[0] = f2bf(v.x); pk[1] = f2bf(v.y); pk[2] = f2bf(v.z); pk[3] = f2bf(v.w);
            *(bf16x4*)&As[r][c4 * 4] = pk;
        }
        // stage B: 128x64 bf16 copy
#pragma unroll
        for (int i = 0; i < 4; ++i) {
            int idx = t + 256 * i;        // 1024 groups of 8
            int r = idx >> 3, c8 = idx & 7;
            *(bf16x8*)&Bs[r][c8 * 8] = *(const bf16x8*)&Wt[(size_t)(n0 + r) * D_ + kt + c8 * 8];
        }
        __syncthreads();
#pragma unroll
        for (int ks = 0; ks < 2; ++ks) {
            bf16x8 a[4], b[4];
#pragma unroll
            for (int m = 0; m < 4; ++m)
                a[m] = *(const bf16x8*)&As[wr * 64 + m * 16 + cl][ks * 32 + g * 8];
#pragma unroll
            for (int n = 0; n < 4; ++n)
                b[n] = *(const bf16x8*)&Bs[wc * 64 + n * 16 + cl][ks * 32 + g * 8];
#pragma unroll
            for (int m = 0; m < 4; ++m)
#pragma unroll
                for (int n = 0; n < 4; ++n)
                    acc[m][n] = __builtin_amdgcn_mfma_f32_16x16x32_bf16(a[m], b[n], acc[m][n], 0, 0, 0);
        }
        __syncthreads();
    }
#pragma unroll
    for (int n = 0; n < 4; ++n) {
        int col = n0 + wc * 64 + n * 16 + cl;
        float bv = bias[col];
#pragma unroll
        for (int m = 0; m < 4; ++m) {
            int rowb = m0 + wr * 64 + m * 16 + g * 4;
#pragma unroll
            for (int j = 0; j < 4; ++j)
                dst[(size_t)(rowb + j) * D_ + col] = f2bf(acc[m][n][j] + bv);
        }
    }
}

// ---------------- flash attention + residual ----------------
// block: 256 threads = 4 waves; each wave 16 q-rows; QBLK=64, KBLK=64.
__global__ __launch_bounds__(256) void attn_kernel(const short* __restrict__ Qb,
                                                   const short* __restrict__ Kb,
                                                   const short* __restrict__ Vb,
                                                   const float* __restrict__ qmask,
                                                   const float* __restrict__ kmask,
                                                   const float* __restrict__ queries,
                                                   float* __restrict__ out) {
    __shared__ short Ks[64][72];
    __shared__ short Vt[64][72];
    __shared__ short Ps[4][16][72];
    const int t = threadIdx.x, lane = t & 63, w = t >> 6;
    const int qt = blockIdx.x * 64, h = blockIdx.y, b = blockIdx.z;
    const int cl = lane & 15, g = lane >> 4;

    // Q fragments (A-operand): row = cl, k = kc*32 + g*8 + j
    bf16x8 qa[2];
    const int qfr = qt + w * 16 + cl;
#pragma unroll
    for (int kc = 0; kc < 2; ++kc)
        qa[kc] = *(const bf16x8*)&Qb[(size_t)(b * T_ + qfr) * D_ + h * DH_ + kc * 32 + g * 8];

    f32x4 o[4] = {};
    float mrow[4], lrow[4];
#pragma unroll
    for (int j = 0; j < 4; ++j) { mrow[j] = -INFINITY; lrow[j] = 0.f; }

    const int ntile = blockIdx.x + 1;
    for (int it = 0; it < ntile; ++it) {
        const int kt = it * 64;
        // stage K (row-major) and V (transposed)
#pragma unroll
        for (int i = 0; i < 2; ++i) {
            int idx = t + 256 * i;        // 512 groups of 8
            int r = idx >> 3, c8 = idx & 7;
            *(bf16x8*)&Ks[r][c8 * 8] =
                *(const bf16x8*)&Kb[(size_t)(b * T_ + kt + r) * D_ + h * DH_ + c8 * 8];
        }
#pragma unroll
        for (int i = 0; i < 2; ++i) {
            int idx = t + 256 * i;
            int r = idx >> 3, c8 = idx & 7;
            bf16x8 v = *(const bf16x8*)&Vb[(size_t)(b * T_ + kt + r) * D_ + h * DH_ + c8 * 8];
#pragma unroll
            for (int j = 0; j < 8; ++j) Vt[c8 * 8 + j][r] = v[j];
        }
        __syncthreads();

        // S = Q K^T  (C: col=cl -> k-row, row=g*4+j -> q-row)
        f32x4 s[4] = {};
#pragma unroll
        for (int nc = 0; nc < 4; ++nc)
#pragma unroll
            for (int kc = 0; kc < 2; ++kc) {
                bf16x8 kb = *(const bf16x8*)&Ks[nc * 16 + cl][kc * 32 + g * 8];
                s[nc] = __builtin_amdgcn_mfma_f32_16x16x32_bf16(qa[kc], kb, s[nc], 0, 0, 0);
            }

        // scale + masks + running max
        float pm[4] = {-INFINITY, -INFINITY, -INFINITY, -INFINITY};
#pragma unroll
        for (int nc = 0; nc < 4; ++nc) {
            int kcol = kt + nc * 16 + cl;
            float km = kmask[b * T_ + kcol];
#pragma unroll
            for (int j = 0; j < 4; ++j) {
                int qr = qt + w * 16 + g * 4 + j;
                float v = s[nc][j] * 0.125f;
                if (kcol > qr || km == 0.0f) v = NEGF;
                s[nc][j] = v;
                pm[j] = fmaxf(pm[j], v);
            }
        }
#pragma unroll
        for (int j = 0; j < 4; ++j) {
            float v = pm[j];
            v = fmaxf(v, __shfl_xor(v, 1));
            v = fmaxf(v, __shfl_xor(v, 2));
            v = fmaxf(v, __shfl_xor(v, 4));
            v = fmaxf(v, __shfl_xor(v, 8));
            pm[j] = v;
        }
        float cf[4];
#pragma unroll
        for (int j = 0; j < 4; ++j) {
            float mn = fmaxf(mrow[j], pm[j]);
            cf[j] = __expf(mrow[j] - mn);
            mrow[j] = mn;
        }
        float psum[4] = {0.f, 0.f, 0.f, 0.f};
#pragma unroll
        for (int nc = 0; nc < 4; ++nc)
#pragma unroll
            for (int j = 0; j < 4; ++j) {
                float p = __expf(s[nc][j] - mrow[j]);
                s[nc][j] = p;
                psum[j] += p;
            }
#pragma unroll
        for (int j = 0; j < 4; ++j) {
            float v = psum[j];
            v += __shfl_xor(v, 1);
            v += __shfl_xor(v, 2);
            v += __shfl_xor(v, 4);
            v += __shfl_xor(v, 8);
            lrow[j] = lrow[j] * cf[j] + v;
        }
#pragma unroll
        for (int dc = 0; dc < 4; ++dc)
#pragma unroll
            for (int j = 0; j < 4; ++j) o[dc][j] *= cf[j];

        // P -> LDS (per-wave region), then PV
#pragma unroll
        for (int nc = 0; nc < 4; ++nc)
#pragma unroll
            for (int j = 0; j < 4; ++j)
                Ps[w][g * 4 + j][nc * 16 + cl] = f2bf(s[nc][j]);
        asm volatile("s_waitcnt lgkmcnt(0)" ::: "memory");
#pragma unroll
        for (int ks = 0; ks < 2; ++ks) {
            bf16x8 pa = *(const bf16x8*)&Ps[w][cl][ks * 32 + g * 8];
#pragma unroll
            for (int dc = 0; dc < 4; ++dc) {
                bf16x8 vb = *(const bf16x8*)&Vt[dc * 16 + cl][ks * 32 + g * 8];
                o[dc] = __builtin_amdgcn_mfma_f32_16x16x32_bf16(pa, vb, o[dc], 0, 0, 0);
            }
        }
        __syncthreads();
    }

    // epilogue: normalize, query mask, residual
#pragma unroll
    for (int j = 0; j < 4; ++j) {
        int qr = qt + w * 16 + g * 4 + j;
        float inv = 1.0f / lrow[j];
        float qm = qmask[b * T_ + qr];
#pragma unroll
        for (int dc = 0; dc < 4; ++dc) {
            size_t idx = (size_t)(b * T_ + qr) * D_ + h * DH_ + dc * 16 + cl;
            out[idx] = o[dc][j] * inv * qm + queries[idx];
        }
    }
}

extern "C" void kernel_launch(void* const* d_in, const int* in_sizes, int n_in,
                              void* d_out, int out_size, void* d_ws, size_t ws_size,
                              hipStream_t stream) {
    const float* queries = (const float*)d_in[0];
    const float* keys    = (const float*)d_in[1];
    const float* value   = (const float*)d_in[2];
    const float* Wq      = (const float*)d_in[3];
    const float* bq      = (const float*)d_in[4];
    const float* Wk      = (const float*)d_in[5];
    const float* bk      = (const float*)d_in[6];
    const float* Wv      = (const float*)d_in[7];
    const float* bv      = (const float*)d_in[8];
    float* out = (float*)d_out;

    char* ws = (char*)d_ws;
    const size_t WT_SZ = (size_t)D_ * D_ * 2;            // 512 KB each
    const size_t QKV_SZ = (size_t)B_ * T_ * D_ * 2;      // 16 MB each
    short* Wtq = (short*)(ws);
    short* Wtk = (short*)(ws + WT_SZ);
    short* Wtv = (short*)(ws + 2 * WT_SZ);
    short* Qb  = (short*)(ws + 3 * WT_SZ);
    short* Kb  = (short*)(ws + 3 * WT_SZ + QKV_SZ);
    short* Vb  = (short*)(ws + 3 * WT_SZ + 2 * QKV_SZ);
    float* qm  = (float*)(ws + 3 * WT_SZ + 3 * QKV_SZ);
    float* km  = qm + B_ * T_;

    wtrans_kernel<<<64, 256, 0, stream>>>(Wq, Wtq);
    wtrans_kernel<<<64, 256, 0, stream>>>(Wk, Wtk);
    wtrans_kernel<<<64, 256, 0, stream>>>(Wv, Wtv);
    mask_kernel<<<B_ * T_ / 4, 256, 0, stream>>>(queries, qm);
    mask_kernel<<<B_ * T_ / 4, 256, 0, stream>>>(keys, km);

    dim3 gg(B_ * T_ / 128, D_ / 128);
    proj_gemm<<<gg, 256, 0, stream>>>(queries, Wtq, bq, Qb);
    proj_gemm<<<gg, 256, 0, stream>>>(keys,    Wtk, bk, Kb);
    proj_gemm<<<gg, 256, 0, stream>>>(value,   Wtv, bv, Vb);

    dim3 ga(T_ / 64, H_, B_);
    attn_kernel<<<ga, 256, 0, stream>>>(Qb, Kb, Vb, qm, km, queries, out);
}

// Round 3
// 159.908 us; speedup vs baseline: 1.5363x; 1.5363x over previous
//
#include <hip/hip_runtime.h>
#include <hip/hip_bf16.h>

#define B_ 16
#define T_ 1024
#define D_ 512
#define H_ 8

typedef __attribute__((ext_vector_type(4))) float f32x4;
typedef __attribute__((ext_vector_type(8))) short bf16x8;
typedef __attribute__((ext_vector_type(4))) short bf16x4;
typedef __attribute__((ext_vector_type(2))) unsigned int u32x2;

__device__ __forceinline__ void gld_lds16(const void* g, void* l) {
    __builtin_amdgcn_global_load_lds((const __attribute__((address_space(1))) void*)g,
                                     (__attribute__((address_space(3))) void*)l, 16, 0, 0);
}

__device__ __forceinline__ short f2bf(float f) {
    union { float f; unsigned u; } v; v.f = f;
    unsigned r = v.u + 0x7FFF + ((v.u >> 16) & 1);
    return (short)(r >> 16);
}

// ---------------- weight transpose: W fp32 [K][N] -> Wt bf16 [N][K] ----------------
__global__ void wtrans_kernel(const float* __restrict__ W, short* __restrict__ Wt) {
    __shared__ float tile[64][65];
    const int t = threadIdx.x;
    const int kt = (blockIdx.x >> 3) * 64;
    const int nt = (blockIdx.x & 7) * 64;
#pragma unroll
    for (int i = 0; i < 4; ++i) {
        int idx = t + i * 256;
        int r = idx >> 4, c4 = idx & 15;
        float4 v = *(const float4*)&W[(kt + r) * D_ + nt + c4 * 4];
        tile[r][c4 * 4 + 0] = v.x; tile[r][c4 * 4 + 1] = v.y;
        tile[r][c4 * 4 + 2] = v.z; tile[r][c4 * 4 + 3] = v.w;
    }
    __syncthreads();
#pragma unroll
    for (int i = 0; i < 2; ++i) {
        int idx = t + i * 256;
        int nr = idx >> 3, c8 = idx & 7;
        bf16x8 pk;
#pragma unroll
        for (int j = 0; j < 8; ++j) pk[j] = f2bf(tile[c8 * 8 + j][nr]);
        *(bf16x8*)&Wt[(nt + nr) * D_ + kt + c8 * 8] = pk;
    }
}

// ---------------- padding masks: row sum -> onv (nonzero) / offv (zero) ----------------
__global__ void mask_kernel(const float* __restrict__ X, float* __restrict__ mask,
                            float onv, float offv) {
    const int w = threadIdx.x >> 6, lane = threadIdx.x & 63;
    const int row = blockIdx.x * 4 + w;
    const float4* p = (const float4*)&X[(size_t)row * D_];
    float s = 0.f;
#pragma unroll
    for (int i = 0; i < 2; ++i) {
        float4 v = p[lane + 64 * i];
        s += v.x + v.y + v.z + v.w;
    }
#pragma unroll
    for (int m = 1; m < 64; m <<= 1) s += __shfl_xor(s, m);
    if (lane == 0) mask[row] = (s != 0.0f) ? onv : offv;
}

// ---------------- projection GEMM: dst[M,512] = bf16(X[M,512] @ W + bias) ----------------
__global__ __launch_bounds__(256) void proj_gemm(const float* __restrict__ X,
                                                 const short* __restrict__ Wt,
                                                 const float* __restrict__ bias,
                                                 short* __restrict__ dst) {
    __shared__ short As[128][72];
    __shared__ short Bs[128][72];
    const int t = threadIdx.x;
    const int m0 = blockIdx.x * 128, n0 = blockIdx.y * 128;
    const int lane = t & 63, w = t >> 6;
    const int wr = w >> 1, wc = w & 1;
    const int cl = lane & 15, g = lane >> 4;
    f32x4 acc[4][4] = {};
    for (int kt = 0; kt < D_; kt += 64) {
#pragma unroll
        for (int i = 0; i < 8; ++i) {
            int idx = t + 256 * i;
            int r = idx >> 4, c4 = idx & 15;
            float4 v = *(const float4*)&X[(size_t)(m0 + r) * D_ + kt + c4 * 4];
            bf16x4 pk;
            pk[0] = f2bf(v.x); pk[1] = f2bf(v.y); pk[2] = f2bf(v.z); pk[3] = f2bf(v.w);
            *(bf16x4*)&As[r][c4 * 4] = pk;
        }
#pragma unroll
        for (int i = 0; i < 4; ++i) {
            int idx = t + 256 * i;
            int r = idx >> 3, c8 = idx & 7;
            *(bf16x8*)&Bs[r][c8 * 8] = *(const bf16x8*)&Wt[(size_t)(n0 + r) * D_ + kt + c8 * 8];
        }
        __syncthreads();
#pragma unroll
        for (int ks = 0; ks < 2; ++ks) {
            bf16x8 a[4], b[4];
#pragma unroll
            for (int m = 0; m < 4; ++m)
                a[m] = *(const bf16x8*)&As[wr * 64 + m * 16 + cl][ks * 32 + g * 8];
#pragma unroll
            for (int n = 0; n < 4; ++n)
                b[n] = *(const bf16x8*)&Bs[wc * 64 + n * 16 + cl][ks * 32 + g * 8];
#pragma unroll
            for (int m = 0; m < 4; ++m)
#pragma unroll
                for (int n = 0; n < 4; ++n)
                    acc[m][n] = __builtin_amdgcn_mfma_f32_16x16x32_bf16(a[m], b[n], acc[m][n], 0, 0, 0);
        }
        __syncthreads();
    }
#pragma unroll
    for (int n = 0; n < 4; ++n) {
        int col = n0 + wc * 64 + n * 16 + cl;
        float bv = bias[col];
#pragma unroll
        for (int m = 0; m < 4; ++m) {
            int rowb = m0 + wr * 64 + m * 16 + g * 4;
#pragma unroll
            for (int j = 0; j < 4; ++j)
                dst[(size_t)(rowb + j) * D_ + col] = f2bf(acc[m][n][j] + bv);
        }
    }
}

// ---------------- V transpose: Vb [B*T][512] -> VtG [(b*8+h)*64+d][T] ----------------
// pi(r) = ((r&7)<<3)|(r>>3) row permutation: b128 writes conflict-free, scalar reads 2-way.
__global__ void vtrans_kernel(const short* __restrict__ Vb, short* __restrict__ VtG) {
    __shared__ short tile[64][72];
    const int t = threadIdx.x;
    const int kt = blockIdx.x & 15;
    const int h  = (blockIdx.x >> 4) & 7;
    const int b  = blockIdx.x >> 7;
#pragma unroll
    for (int i = 0; i < 2; ++i) {
        int idx = t + i * 256;
        int r = idx >> 3, c8 = idx & 7;
        *(bf16x8*)&tile[((r & 7) << 3) | (r >> 3)][c8 * 8] =
            *(const bf16x8*)&Vb[(size_t)(b * T_ + kt * 64 + r) * D_ + h * 64 + c8 * 8];
    }
    __syncthreads();
#pragma unroll
    for (int i = 0; i < 2; ++i) {
        int idx = t + i * 256;
        int d = idx >> 3, r8 = idx & 7;
        bf16x8 pk;
#pragma unroll
        for (int j = 0; j < 8; ++j) pk[j] = tile[(j << 3) | r8][d];
        *(bf16x8*)&VtG[(size_t)((b * 8 + h) * 64 + d) * T_ + kt * 64 + r8 * 8] = pk;
    }
}

// ---------------- flash attention + residual ----------------
// 4 waves, QBLK=128 (32 q/wave), KVBLK=64, dbuf K/V^T via global_load_lds (XOR-swizzled src).
__global__ __launch_bounds__(256, 3) void attn_kernel(
    const short* __restrict__ Qb, const short* __restrict__ Kb,
    const short* __restrict__ VtG, const float* __restrict__ qmask,
    const float* __restrict__ kbias, const float* __restrict__ queries,
    float* __restrict__ out) {
    __shared__ char KV[2][2][8192];      // [buf][K=0 / V^T=1]
    __shared__ short Ps[4][32][72];      // per-wave P tile [q][k]
    const int t = threadIdx.x, lane = t & 63, w = t >> 6;
    const int cl = lane & 15, g = lane >> 4;
    const int gid = blockIdx.x;
    const int bx = (int)((0x34251607u >> ((gid & 7) * 4)) & 7u);
    const int h = (gid >> 3) & 7, b = gid >> 6;
    const int qt = bx * 128;
    const int nt = 2 * bx + 2;

    // staging source indices (granule XOR pre-permuted so linear LDS + XOR-read works)
    const int rS0 = t >> 3,       cS0 = ((t & 7) ^ (rS0 & 7)) * 8;
    const int t2 = t + 256;
    const int rS1 = t2 >> 3,      cS1 = ((t2 & 7) ^ (rS1 & 7)) * 8;
    const short* kS0 = Kb  + ((size_t)(b * T_) + rS0) * D_ + h * 64 + cS0;
    const short* kS1 = Kb  + ((size_t)(b * T_) + rS1) * D_ + h * 64 + cS1;
    const short* vS0 = VtG + (size_t)((b * 8 + h) * 64 + rS0) * T_ + cS0;
    const short* vS1 = VtG + (size_t)((b * 8 + h) * 64 + rS1) * T_ + cS1;

    // Q B-fragments: col = q = nq*16+cl, elems d = kc*32+g*8+j
    bf16x8 qb[2][2];
    const int q0 = qt + w * 32 + cl;
#pragma unroll
    for (int nq = 0; nq < 2; ++nq)
#pragma unroll
        for (int kc = 0; kc < 2; ++kc)
            qb[nq][kc] = *(const bf16x8*)&Qb[(size_t)(b * T_ + q0 + nq * 16) * D_ + h * 64 + kc * 32 + g * 8];

    // prologue: stage tile 0 into buf 0
    gld_lds16(kS0, &KV[0][0][0]    + w * 1024);
    gld_lds16(kS1, &KV[0][0][4096] + w * 1024);
    gld_lds16(vS0, &KV[0][1][0]    + w * 1024);
    gld_lds16(vS1, &KV[0][1][4096] + w * 1024);

    f32x4 o[2][4] = {};
    float m[2] = {-3e30f, -3e30f}, l[2] = {0.f, 0.f};
    const float csc = 0.125f * 1.44269504088896f;   // 1/sqrt(64) * log2(e)
    const float* kbp = kbias + b * T_;

    for (int it = 0; it < nt; ++it) {
        const int buf = it & 1;
        __syncthreads();   // implicit vmcnt(0): tile-it staged, all waves done with buf^1

        // key-bias loads FIRST (oldest vmem -> their wait won't drain the prefetch)
        f32x4 kb4[4];
#pragma unroll
        for (int nc = 0; nc < 4; ++nc)
            kb4[nc] = *(const f32x4*)&kbp[it * 64 + nc * 16 + g * 4];

        if (it + 1 < nt) {   // prefetch next tile into buf^1 (flies during compute)
            const int kt2 = (it + 1) * 64;
            char* db = &KV[buf ^ 1][0][0];
            gld_lds16(kS0 + (size_t)kt2 * D_, db + w * 1024);
            gld_lds16(kS1 + (size_t)kt2 * D_, db + 4096 + w * 1024);
            gld_lds16(vS0 + kt2, db + 8192 + w * 1024);
            gld_lds16(vS1 + kt2, db + 8192 + 4096 + w * 1024);
        }

        const char* Kl = &KV[buf][0][0];
        const char* Vl = &KV[buf][1][0];

        // QK^T swapped: s[nq][nc][j] = S[k = nc*16+g*4+j][q = nq*16+cl]
        f32x4 s[2][4] = {};
#pragma unroll
        for (int kc = 0; kc < 2; ++kc)
#pragma unroll
            for (int nc = 0; nc < 4; ++nc) {
                bf16x8 a = *(const bf16x8*)(Kl + (nc * 16 + cl) * 128 + (((kc * 4 + g) ^ (cl & 7)) << 4));
                s[0][nc] = __builtin_amdgcn_mfma_f32_16x16x32_bf16(a, qb[0][kc], s[0][nc], 0, 0, 0);
                s[1][nc] = __builtin_amdgcn_mfma_f32_16x16x32_bf16(a, qb[1][kc], s[1][nc], 0, 0, 0);
            }

        // scale + key bias + causal (last 2 tiles), lane-local max
        const int kt = it * 64;
        const bool ctile = (it >= 2 * bx);
        float pm[2] = {-3e30f, -3e30f};
#pragma unroll
        for (int nc = 0; nc < 4; ++nc)
#pragma unroll
            for (int nq = 0; nq < 2; ++nq) {
                const int qr = qt + w * 32 + nq * 16 + cl;
#pragma unroll
                for (int j = 0; j < 4; ++j) {
                    float v = fmaf(s[nq][nc][j], csc, kb4[nc][j]);
                    if (ctile && (kt + nc * 16 + g * 4 + j > qr)) v = -3e30f;
                    s[nq][nc][j] = v;
                    pm[nq] = fmaxf(pm[nq], v);
                }
            }
#pragma unroll
        for (int nq = 0; nq < 2; ++nq) {
            pm[nq] = fmaxf(pm[nq], __shfl_xor(pm[nq], 16));
            pm[nq] = fmaxf(pm[nq], __shfl_xor(pm[nq], 32));
        }
        // defer-max: skip O/l rescale while max grows < 8 (exp2 domain, P <= 256)
        if (__any((pm[0] > m[0] + 8.f) || (pm[1] > m[1] + 8.f))) {
#pragma unroll
            for (int nq = 0; nq < 2; ++nq) {
                float mn = fmaxf(m[nq], pm[nq]);
                float cf;
                asm("v_exp_f32 %0, %1" : "=v"(cf) : "v"(m[nq] - mn));
                l[nq] *= cf;
                m[nq] = mn;
#pragma unroll
                for (int j = 0; j < 4; ++j) {
                    float cfj = __shfl(cf, g * 4 + j);
#pragma unroll
                    for (int dc = 0; dc < 4; ++dc) o[nq][dc][j] *= cfj;
                }
            }
        }
        float ps[2] = {0.f, 0.f};
#pragma unroll
        for (int nq = 0; nq < 2; ++nq)
#pragma unroll
            for (int nc = 0; nc < 4; ++nc)
#pragma unroll
                for (int j = 0; j < 4; ++j) {
                    float p;
                    asm("v_exp_f32 %0, %1" : "=v"(p) : "v"(s[nq][nc][j] - m[nq]));
                    s[nq][nc][j] = p;
                    ps[nq] += p;
                }
#pragma unroll
        for (int nq = 0; nq < 2; ++nq) {
            ps[nq] += __shfl_xor(ps[nq], 16);
            ps[nq] += __shfl_xor(ps[nq], 32);
            l[nq] += ps[nq];
        }

        // P -> per-wave LDS in standard [q][k] order (cvt_pk + b64 writes)
#pragma unroll
        for (int nq = 0; nq < 2; ++nq)
#pragma unroll
            for (int nc = 0; nc < 4; ++nc) {
                u32x2 pw;
                asm("v_cvt_pk_bf16_f32 %0, %1, %2" : "=v"(pw[0]) : "v"(s[nq][nc][0]), "v"(s[nq][nc][1]));
                asm("v_cvt_pk_bf16_f32 %0, %1, %2" : "=v"(pw[1]) : "v"(s[nq][nc][2]), "v"(s[nq][nc][3]));
                *(u32x2*)&Ps[w][nq * 16 + cl][nc * 16 + g * 4] = pw;
            }

        // PV: A = P (rows q=cl), B = V^T rows d (XOR-swizzled read)
#pragma unroll
        for (int ks = 0; ks < 2; ++ks) {
            bf16x8 pa0 = *(const bf16x8*)&Ps[w][cl][ks * 32 + g * 8];
            bf16x8 pa1 = *(const bf16x8*)&Ps[w][16 + cl][ks * 32 + g * 8];
#pragma unroll
            for (int dc = 0; dc < 4; ++dc) {
                bf16x8 vv = *(const bf16x8*)(Vl + (dc * 16 + cl) * 128 + (((ks * 4 + g) ^ (cl & 7)) << 4));
                o[0][dc] = __builtin_amdgcn_mfma_f32_16x16x32_bf16(pa0, vv, o[0][dc], 0, 0, 0);
                o[1][dc] = __builtin_amdgcn_mfma_f32_16x16x32_bf16(pa1, vv, o[1][dc], 0, 0, 0);
            }
        }
    }

    // epilogue: normalize, query mask, residual
#pragma unroll
    for (int nq = 0; nq < 2; ++nq) {
        float inv = 1.0f / l[nq];
#pragma unroll
        for (int j = 0; j < 4; ++j) {
            float linv = __shfl(inv, g * 4 + j);
            const int q = qt + w * 32 + nq * 16 + g * 4 + j;
            const float sc2 = linv * qmask[b * T_ + q];
            const size_t base = (size_t)(b * T_ + q) * D_ + h * 64;
#pragma unroll
            for (int dc = 0; dc < 4; ++dc) {
                const size_t idx = base + dc * 16 + cl;
                out[idx] = o[nq][dc][j] * sc2 + queries[idx];
            }
        }
    }
}

extern "C" void kernel_launch(void* const* d_in, const int* in_sizes, int n_in,
                              void* d_out, int out_size, void* d_ws, size_t ws_size,
                              hipStream_t stream) {
    const float* queries = (const float*)d_in[0];
    const float* keys    = (const float*)d_in[1];
    const float* value   = (const float*)d_in[2];
    const float* Wq      = (const float*)d_in[3];
    const float* bq      = (const float*)d_in[4];
    const float* Wk      = (const float*)d_in[5];
    const float* bk      = (const float*)d_in[6];
    const float* Wv      = (const float*)d_in[7];
    const float* bv      = (const float*)d_in[8];
    float* out = (float*)d_out;

    char* ws = (char*)d_ws;
    const size_t WT_SZ  = (size_t)D_ * D_ * 2;        // 512 KB
    const size_t QKV_SZ = (size_t)B_ * T_ * D_ * 2;   // 16 MB
    short* Wtq = (short*)(ws);
    short* Wtk = (short*)(ws + WT_SZ);
    short* Wtv = (short*)(ws + 2 * WT_SZ);
    short* Qb  = (short*)(ws + 3 * WT_SZ);
    short* Kb  = (short*)(ws + 3 * WT_SZ + QKV_SZ);
    short* Vb  = (short*)(ws + 3 * WT_SZ + 2 * QKV_SZ);
    short* VtG = (short*)(ws + 3 * WT_SZ + 3 * QKV_SZ);
    float* qm  = (float*)(ws + 3 * WT_SZ + 4 * QKV_SZ);
    float* kb  = qm + B_ * T_;

    wtrans_kernel<<<64, 256, 0, stream>>>(Wq, Wtq);
    wtrans_kernel<<<64, 256, 0, stream>>>(Wk, Wtk);
    wtrans_kernel<<<64, 256, 0, stream>>>(Wv, Wtv);
    mask_kernel<<<B_ * T_ / 4, 256, 0, stream>>>(queries, qm, 1.0f, 0.0f);
    mask_kernel<<<B_ * T_ / 4, 256, 0, stream>>>(keys, kb, 0.0f, -3e30f);

    dim3 gg(B_ * T_ / 128, D_ / 128);
    proj_gemm<<<gg, 256, 0, stream>>>(queries, Wtq, bq, Qb);
    proj_gemm<<<gg, 256, 0, stream>>>(keys,    Wtk, bk, Kb);
    proj_gemm<<<gg, 256, 0, stream>>>(value,   Wtv, bv, Vb);

    vtrans_kernel<<<B_ * H_ * (T_ / 64), 256, 0, stream>>>(Vb, VtG);

    attn_kernel<<<B_ * H_ * (T_ / 128), 256, 0, stream>>>(Qb, Kb, VtG, qm, kb, queries, out);
}